// Round 1
// baseline (313.766 us; speedup 1.0000x reference)
//
#include <hip/hip_runtime.h>
#include <hip/hip_bf16.h>
#include <stdint.h>

// Problem constants
#define NB 2
#define NT 4096
#define NC 768
#define NHEAD 12
#define HS 64
#define MTOK (NB * NT)      // 8192
#define C3 (3 * NC)         // 2304

typedef __bf16 bf16x8 __attribute__((ext_vector_type(8)));
typedef float f32x4 __attribute__((ext_vector_type(4)));

#define KSCALE_LOG2E 0.18033688011f   // (1/sqrt(64)) * log2(e)

__device__ __forceinline__ unsigned short f2bf(float f) {  // RNE
  union { float f; uint32_t u; } v; v.f = f;
  uint32_t r = v.u + 0x7fffu + ((v.u >> 16) & 1u);
  return (unsigned short)(r >> 16);
}
__device__ __forceinline__ unsigned short bft(float f) {   // truncate
  return (unsigned short)(__builtin_bit_cast(unsigned int, f) >> 16);
}
// pack two floats as truncated bf16 pair: low elem = a, high elem = b
__device__ __forceinline__ uint32_t pack_bf2(float a, float b) {
  return (__builtin_bit_cast(uint32_t, b) & 0xffff0000u) |
         (__builtin_bit_cast(uint32_t, a) >> 16);
}

// async global->LDS, 16B per lane: lane i lands at ldsbase + i*16B.
__device__ __forceinline__ void gload_lds16(const unsigned short* g, unsigned short* ldsbase) {
  __builtin_amdgcn_global_load_lds(
      (const __attribute__((address_space(1))) unsigned int*)g,
      (__attribute__((address_space(3))) unsigned int*)ldsbase, 16, 0, 0);
}

__device__ __forceinline__ f32x4 mfma16(bf16x8 a, bf16x8 b, f32x4 c) {
  return __builtin_amdgcn_mfma_f32_16x16x32_bf16(a, b, c, 0, 0, 0);
}

// ---------------- prep: coalesced LDS-tiled transposes + x cast ----------------
__global__ __launch_bounds__(256) void prep(
    const float* __restrict__ x, const float* __restrict__ wa, const float* __restrict__ wp,
    unsigned short* __restrict__ xb, unsigned short* __restrict__ waT,
    unsigned short* __restrict__ wpT) {
  const int bx = blockIdx.x;
  if (bx < 576) {
    __shared__ float tile[64][65];
    const float* src; unsigned short* dst;
    int srcN, dstN, k0, n0, qscale;
    if (bx < 432) {
      src = wa; dst = waT; srcN = C3; dstN = NC; qscale = 1;
      k0 = (bx / 36) * 64; n0 = (bx % 36) * 64;
    } else {
      const int t = bx - 432;
      src = wp; dst = wpT; srcN = NC; dstN = NC; qscale = 0;
      k0 = (t / 12) * 64; n0 = (t % 12) * 64;
    }
    const int tr = threadIdx.x >> 4;        // 0..15
    const int tc = (threadIdx.x & 15) * 4;  // 0,4,..,60
#pragma unroll
    for (int p = 0; p < 4; ++p) {
      const int r = p * 16 + tr;
      const float4 v = *reinterpret_cast<const float4*>(src + (size_t)(k0 + r) * srcN + n0 + tc);
      tile[r][tc + 0] = v.x; tile[r][tc + 1] = v.y;
      tile[r][tc + 2] = v.z; tile[r][tc + 3] = v.w;
    }
    __syncthreads();
#pragma unroll
    for (int p = 0; p < 4; ++p) {
      const int n = p * 16 + tr;   // output row = source column n0+n
      const float sc = (qscale && (n0 + n) < NC) ? KSCALE_LOG2E : 1.0f;
      ushort4 o;
      o.x = f2bf(tile[tc + 0][n] * sc); o.y = f2bf(tile[tc + 1][n] * sc);
      o.z = f2bf(tile[tc + 2][n] * sc); o.w = f2bf(tile[tc + 3][n] * sc);
      *reinterpret_cast<ushort4*>(dst + (size_t)(n0 + n) * dstN + k0 + tc) = o;
    }
  } else {
    const int gid = (bx - 576) * 256 + threadIdx.x;   // < MTOK*NC/4
    const float4 v = reinterpret_cast<const float4*>(x)[gid];
    ushort4 o;
    o.x = f2bf(v.x); o.y = f2bf(v.y); o.z = f2bf(v.z); o.w = f2bf(v.w);
    reinterpret_cast<ushort4*>(xb)[gid] = o;
  }
}

// ---------------- GEMM 128x128: C[M,N] = A[M,K] @ Bt[N,K]^T ----------------
// OUT_BF16=1 (gemm1): blocks with col0 >= 2*NC hold the V tile -> transpose
// in-block via smem (16B-chunk XOR swizzle) and write straight to vT
// [B*NH][HS][T]; qkvb's V slice is never written. Other blocks write qkvb rows.
template <int OUT_BF16>
__global__ __launch_bounds__(256) void gemm128(
    const unsigned short* __restrict__ A,   // [M][K]
    const unsigned short* __restrict__ Bt,  // [N][K]
    void* __restrict__ Cout,
    unsigned short* __restrict__ vT,        // used only by OUT_BF16 V-blocks
    int M, int N, int K) {
  __shared__ unsigned short smem[2 * 128 * 64];
  unsigned short* As = smem;
  unsigned short* Bs = smem + 128 * 64;

  const int tid = threadIdx.x;
  const int wave = tid >> 6;
  const int lane = tid & 63;
  const int li = lane & 15;
  const int lq = lane >> 4;
  const int wm = wave & 1;
  const int wn = wave >> 1;
  const int row0 = blockIdx.y * 128;
  const int col0 = blockIdx.x * 128;

  const int crow = lane >> 3;
  const int cchunk = ((lane & 7) ^ crow) * 8;

  f32x4 acc[4][4] = {};

  for (int k0 = 0; k0 < K; k0 += 64) {
#pragma unroll
    for (int i = 0; i < 4; ++i) {
      const int R = wave * 32 + i * 8;
      gload_lds16(A + (size_t)(row0 + R + crow) * K + k0 + cchunk, &As[R * 64]);
      gload_lds16(Bt + (size_t)(col0 + R + crow) * K + k0 + cchunk, &Bs[R * 64]);
    }
    __syncthreads();

#pragma unroll
    for (int ks = 0; ks < 2; ++ks) {
      bf16x8 af[4], bf[4];
#pragma unroll
      for (int f = 0; f < 4; ++f) {
        const int arow = wm * 64 + f * 16 + li;
        af[f] = *reinterpret_cast<const bf16x8*>(&As[arow * 64 + (((ks * 4 + lq) ^ (li & 7)) << 3)]);
        const int brow = wn * 64 + f * 16 + li;
        bf[f] = *reinterpret_cast<const bf16x8*>(&Bs[brow * 64 + (((ks * 4 + lq) ^ (li & 7)) << 3)]);
      }
#pragma unroll
      for (int fa = 0; fa < 4; ++fa)
#pragma unroll
        for (int fb = 0; fb < 4; ++fb)
          acc[fa][fb] = mfma16(af[fa], bf[fb], acc[fa][fb]);
    }
    __syncthreads();   // also protects smem reuse in the fused epilogue
  }

  if (OUT_BF16) {
    if (col0 >= 2 * NC) {
      // ---- fused V transpose: acc -> smem[c][t] -> vT[bh][d][t] ----
      const int b = row0 >> 12;            // row0 / NT
      const int t0r = row0 & (NT - 1);
      const int h0 = (col0 - 2 * NC) >> 6;
      // write phase: value at (c = head-col, t = token) with 16B-chunk XOR swizzle
#pragma unroll
      for (int fa = 0; fa < 4; ++fa) {
#pragma unroll
        for (int fb = 0; fb < 4; ++fb) {
          const int cc = wn * 64 + fb * 16 + li;
#pragma unroll
          for (int r = 0; r < 4; ++r) {
            const int tt = wm * 64 + fa * 16 + lq * 4 + r;
            const int slot = cc * 16 + ((tt >> 3) ^ (cc & 15));
            smem[slot * 8 + (tt & 7)] = f2bf(acc[fa][fb][r]);
          }
        }
      }
      __syncthreads();
      // read phase: 16 lanes cover one c-row's 16 chunks -> 256B coalesced stores
      const int ch = tid & 15;
#pragma unroll
      for (int j = 0; j < 8; ++j) {
        const int cc = (tid >> 4) + 16 * j;
        const uint4 v = *reinterpret_cast<const uint4*>(
            smem + (size_t)(cc * 16 + (ch ^ (cc & 15))) * 8);
        const int bh = b * NHEAD + h0 + (cc >> 6);
        const int d = cc & 63;
        *reinterpret_cast<uint4*>(vT + (size_t)bh * HS * NT + (size_t)d * NT + t0r + ch * 8) = v;
      }
    } else {
      unsigned short* Cb = (unsigned short*)Cout;
#pragma unroll
      for (int fa = 0; fa < 4; ++fa) {
        const int gr = row0 + wm * 64 + fa * 16 + lq * 4;
#pragma unroll
        for (int fb = 0; fb < 4; ++fb) {
          const int gc = col0 + wn * 64 + fb * 16 + li;
#pragma unroll
          for (int r = 0; r < 4; ++r)
            Cb[(size_t)(gr + r) * N + gc] = f2bf(acc[fa][fb][r]);
        }
      }
    }
  } else {
    float* Cf = (float*)Cout;
#pragma unroll
    for (int fa = 0; fa < 4; ++fa) {
      const int gr = row0 + wm * 64 + fa * 16 + lq * 4;
#pragma unroll
      for (int fb = 0; fb < 4; ++fb) {
        const int gc = col0 + wn * 64 + fb * 16 + li;
#pragma unroll
        for (int r = 0; r < 4; ++r)
          Cf[(size_t)(gr + r) * N + gc] = acc[fa][fb][r];
      }
    }
  }
}

// ---------------- Flash attention: balanced split-KV chunks (8 tiles) ----------------
// Round-9 best config: chunks of <=8 KV tiles, 144 per (b,h), grid 3456.
// This round: (1) K/V double-buffered in LDS via global_load_lds with
// pre-swizzled global source (linear LDS dest per wave) -> ONE barrier/tile,
// no reg-staging; (2) operand-swapped QK^T (S^T in C-layout) so each lane
// holds 4 runs of 4 consecutive k per q-row -> packed ds_write_b64 P-stores
// (4 per strip instead of 16 ds_write_u16); (3) s_setprio around MFMA.
// Unnormalized exp (Q pre-scaled in waT, log2 domain): partials merge
// additively via fp32 atomics; l on the MFMA pipe.

// S^T exp-store: lane (li,lq) holds S[q = SBASE+li][k = t0 + n*16 + lq*4 + r].
// Ps layout identical to reads: logical 8-elem chunk c of row prow lives at
// physical chunk c ^ (prow&7).
#define EXP_STORE_T(S, SBASE, DOMASK)                                          \
  do {                                                                         \
    const int prow_ = (SBASE) + li;                                            \
    const int sw_ = prow_ & 7;                                                 \
    const int qtok_ = q0 + prow_;                                              \
    _Pragma("unroll") for (int n = 0; n < 4; ++n) {                            \
      float v0 = S[n][0], v1 = S[n][1], v2 = S[n][2], v3 = S[n][3];            \
      if (DOMASK) {                                                            \
        const int kt_ = t0 + n * 16 + lq * 4;                                  \
        if (kt_ + 0 > qtok_) v0 = -INFINITY;                                   \
        if (kt_ + 1 > qtok_) v1 = -INFINITY;                                   \
        if (kt_ + 2 > qtok_) v2 = -INFINITY;                                   \
        if (kt_ + 3 > qtok_) v3 = -INFINITY;                                   \
      }                                                                        \
      const uint32_t lo_ = pack_bf2(__builtin_amdgcn_exp2f(v0),                \
                                    __builtin_amdgcn_exp2f(v1));               \
      const uint32_t hi_ = pack_bf2(__builtin_amdgcn_exp2f(v2),                \
                                    __builtin_amdgcn_exp2f(v3));               \
      *reinterpret_cast<uint2*>(Ps + prow_ * 64 +                              \
          (((n * 2 + (lq >> 1)) ^ sw_) << 3) + (lq & 1) * 4) =                 \
          make_uint2(lo_, hi_);                                                \
    }                                                                          \
  } while (0)

__global__ __launch_bounds__(256) void attn(
    const unsigned short* __restrict__ qkv,   // [B][T][3C] (V slice unused)
    const unsigned short* __restrict__ vT,    // [B*NH][HS][T]
    float* __restrict__ Oacc,                 // [MTOK][NC] fp32, zeroed
    float* __restrict__ lacc) {               // [B*NH][NT]  fp32, zeroed
  __shared__ unsigned short Ks[2][64 * 64];
  __shared__ unsigned short Vts[2][64 * 64];
  __shared__ unsigned short Ps[128 * 64];

  const int tid = threadIdx.x;
  const int wave = tid >> 6;
  const int lane = tid & 63;
  const int li = lane & 15;
  const int lq = lane >> 4;

  // ---- chunk decode: c in [0,144) -> (q-tile qi, chunk ck) ----
  const int c = 143 - (int)blockIdx.x;
  int g = 0;
#pragma unroll
  for (int gg = 1; gg < 8; ++gg)
    if (2 * gg * (gg + 1) <= c) g = gg;       // group g: q-tiles 4g..4g+3, g+1 chunks each
  const int rem = c - 2 * g * (g + 1);
  const int dq = rem / (g + 1);
  const int qi = 4 * g + dq;                  // q-tile 0..31
  const int ck = rem - dq * (g + 1);          // chunk 0..g
  const int q0 = qi * 128;
  const int ntile = 2 * qi + 2;
  const int tauS = ck * 8;
  const int tauE = (tauS + 8 < ntile) ? tauS + 8 : ntile;

  const int h = blockIdx.y;
  const int b = blockIdx.z;
  const int bh = b * NHEAD + h;

  const size_t baseQ = (size_t)b * NT * C3 + (size_t)h * HS;
  const size_t baseK = baseQ + NC;
  const unsigned short* kq = qkv + baseK;
  const unsigned short* vbase = vT + (size_t)bh * HS * NT;

  const int sb0 = wave * 16;
  const int sb1 = 64 + wave * 16;

  // Q fragments (pre-scaled via waT); same bytes serve as MFMA B-operand.
  bf16x8 aq0[2], aq1[2];
#pragma unroll
  for (int ks = 0; ks < 2; ++ks) {
    aq0[ks] = *reinterpret_cast<const bf16x8*>(qkv + baseQ + (size_t)(q0 + sb0 + li) * C3 + ks * 32 + lq * 8);
    aq1[ks] = *reinterpret_cast<const bf16x8*>(qkv + baseQ + (size_t)(q0 + sb1 + li) * C3 + ks * 32 + lq * 8);
  }

  // all-ones B fragment for l row-sums on the MFMA pipe
  bf16x8 vones;
#pragma unroll
  for (int i = 0; i < 8; ++i) vones[i] = (__bf16)1.0f;

  f32x4 o0[4] = {}, o1[4] = {};
  f32x4 la0 = {}, la1 = {};

  // ---- gload staging geometry: per wave, 2 calls x 8 rows for K and V ----
  // DMA writes linear (wave-uniform LDS base + lane*16B); the XOR swizzle is
  // applied on the per-lane GLOBAL address instead (row&7 == lane>>3 here).
  const int grow = lane >> 3;               // row within 8-row group
  const int gch = (lane & 7) ^ grow;        // pre-swizzled 16B chunk
  const int wr0 = wave * 8;                 // uniform row bases
  const int wr1 = wave * 8 + 32;

#define STAGE(TAU, BUFI)                                                        \
  do {                                                                          \
    const int t0s_ = (TAU) * 64;                                                \
    gload_lds16(kq + (size_t)(t0s_ + wr0 + grow) * C3 + gch * 8,                \
                &Ks[BUFI][wr0 * 64]);                                           \
    gload_lds16(kq + (size_t)(t0s_ + wr1 + grow) * C3 + gch * 8,                \
                &Ks[BUFI][wr1 * 64]);                                           \
    gload_lds16(vbase + (size_t)(wr0 + grow) * NT + t0s_ + gch * 8,             \
                &Vts[BUFI][wr0 * 64]);                                          \
    gload_lds16(vbase + (size_t)(wr1 + grow) * NT + t0s_ + gch * 8,             \
                &Vts[BUFI][wr1 * 64]);                                          \
  } while (0)

  STAGE(tauS, 0);

  int cur = 0;
  for (int tau = tauS; tau < tauE; ++tau) {
    const int t0 = tau * 64;
    // implicit vmcnt(0)+lgkmcnt(0) drain: publishes buf[cur] DMA writes and
    // guarantees prior tile's LDS reads are done before next STAGE overwrite.
    __syncthreads();
    if (tau + 1 < tauE) STAGE(tau + 1, cur ^ 1);

    const bool do0 = (t0 != q0 + 64);   // strip0 dead on very last tile
    const unsigned short* Kc = Ks[cur];
    const unsigned short* Vc = Vts[cur];

    // ---- S^T = K Q^T (swapped operands: lane li owns q-row sb+li) ----
    f32x4 s0[4], s1[4];
    {
      const f32x4 z = {};
      __builtin_amdgcn_s_setprio(1);
#pragma unroll
      for (int n = 0; n < 4; ++n) {
        const bf16x8 bk0 = *reinterpret_cast<const bf16x8*>(
            Kc + (n * 16 + li) * 64 + ((lq ^ (li & 7)) << 3));
        const bf16x8 bk1 = *reinterpret_cast<const bf16x8*>(
            Kc + (n * 16 + li) * 64 + (((4 + lq) ^ (li & 7)) << 3));
        s1[n] = mfma16(bk0, aq1[0], z);
        s1[n] = mfma16(bk1, aq1[1], s1[n]);
        if (do0) {
          s0[n] = mfma16(bk0, aq0[0], z);
          s0[n] = mfma16(bk1, aq0[1], s0[n]);
        }
      }
      __builtin_amdgcn_s_setprio(0);
    }

    // ---- exp phase (block-uniform case split), packed b64 stores ----
    if (t0 < q0) {
      EXP_STORE_T(s0, sb0, false);
      EXP_STORE_T(s1, sb1, false);
    } else if (t0 == q0) {
      EXP_STORE_T(s0, sb0, true);
      EXP_STORE_T(s1, sb1, false);
    } else {
      EXP_STORE_T(s1, sb1, true);
    }

    // Ps rows are wave-private: LDS completion suffices (no barrier)
    asm volatile("s_waitcnt lgkmcnt(0)" ::: "memory");

    // ---- O += P V ; l += P . ones (MFMA pipe) ----
    __builtin_amdgcn_s_setprio(1);
#pragma unroll
    for (int ks = 0; ks < 2; ++ks) {
      const int swz = ((ks * 4 + lq) ^ (li & 7)) << 3;
      const bf16x8 ap0 = *reinterpret_cast<const bf16x8*>(Ps + (sb0 + li) * 64 + swz);
      const bf16x8 ap1 = *reinterpret_cast<const bf16x8*>(Ps + (sb1 + li) * 64 + swz);
      if (do0) la0 = mfma16(ap0, vones, la0);
      la1 = mfma16(ap1, vones, la1);
#pragma unroll
      for (int n = 0; n < 4; ++n) {
        const bf16x8 bv = *reinterpret_cast<const bf16x8*>(Vc + (n * 16 + li) * 64 + swz);
        if (do0) o0[n] = mfma16(ap0, bv, o0[n]);
        o1[n] = mfma16(ap1, bv, o1[n]);
      }
    }
    __builtin_amdgcn_s_setprio(0);
    cur ^= 1;
  }
#undef STAGE

  // ---- atomic partial accumulation (unnormalized; la* uniform across li) ----
  const size_t obase = (size_t)b * NT * NC + (size_t)h * HS;
  float* lrow = lacc + (size_t)bh * NT;
#pragma unroll
  for (int r = 0; r < 4; ++r) {
    const int row = q0 + sb0 + lq * 4 + r;
    if (li == 0) atomicAdd(&lrow[row], la0[r]);
#pragma unroll
    for (int n = 0; n < 4; ++n)
      atomicAdd(&Oacc[obase + (size_t)row * NC + n * 16 + li], o0[n][r]);
  }
#pragma unroll
  for (int r = 0; r < 4; ++r) {
    const int row = q0 + sb1 + lq * 4 + r;
    if (li == 0) atomicAdd(&lrow[row], la1[r]);
#pragma unroll
    for (int n = 0; n < 4; ++n)
      atomicAdd(&Oacc[obase + (size_t)row * NC + n * 16 + li], o1[n][r]);
  }
}

// ---------------- finalize: aob = bf16(Oacc / l) ----------------
__global__ __launch_bounds__(256) void finalize(
    const float* __restrict__ Oacc, const float* __restrict__ lacc,
    unsigned short* __restrict__ aob) {
  const int idx4 = (blockIdx.x * 256 + threadIdx.x);
  if (idx4 >= MTOK * NC / 4) return;
  const int idx = idx4 * 4;
  const int row = idx / NC;
  const int cc = idx - row * NC;
  const int h = cc >> 6;
  const int b = row >> 12;            // NT = 4096
  const int t = row & (NT - 1);
  const float inv = 1.0f / lacc[(size_t)(b * NHEAD + h) * NT + t];
  const float4 v = reinterpret_cast<const float4*>(Oacc)[idx4];
  ushort4 o;
  o.x = bft(v.x * inv); o.y = bft(v.y * inv);
  o.z = bft(v.z * inv); o.w = bft(v.w * inv);
  reinterpret_cast<ushort4*>(aob)[idx4] = o;
}

// ---------------- launch ----------------
extern "C" void kernel_launch(void* const* d_in, const int* in_sizes, int n_in,
                              void* d_out, int out_size, void* d_ws, size_t ws_size,
                              hipStream_t stream) {
  const float* x = (const float*)d_in[0];       // [B,T,C]
  const float* w_attn = (const float*)d_in[1];  // [C, 3C]
  const float* w_proj = (const float*)d_in[2];  // [C, C]
  float* outp = (float*)d_out;

  // ws layout (Oacc aliases xb/waT, which die after gemm1):
  char* w = (char*)d_ws;
  float* Oacc = (float*)w;
  unsigned short* xb = (unsigned short*)w;                       // aliases Oacc (pre-attn)
  unsigned short* waT = xb + (size_t)MTOK * NC;                  // aliases Oacc tail
  float* lacc = Oacc + (size_t)MTOK * NC;
  unsigned short* qkvb = (unsigned short*)(lacc + (size_t)NB * NHEAD * NT);
  unsigned short* aob  = qkvb + (size_t)MTOK * C3;               // [MTOK][NC] bf16
  unsigned short* vTb  = aob + (size_t)MTOK * NC;                // [B*NH][HS][T]
  unsigned short* wpT  = vTb + (size_t)MTOK * NC;                // [NC][NC] bf16

  // prep: 576 transpose tiles + x-cast blocks
  prep<<<576 + MTOK * NC / 4 / 256, 256, 0, stream>>>(x, w_attn, w_proj, xb, waT, wpT);

  // qkv = x @ w_attn (Q rows of waT pre-scaled); V blocks write vTb directly
  gemm128<1><<<dim3(C3 / 128, MTOK / 128), 256, 0, stream>>>(xb, waT, qkvb, vTb, MTOK, C3, NC);

  // zero partial accumulators (xb/waT now dead)
  hipMemsetAsync(Oacc, 0, ((size_t)MTOK * NC + (size_t)NB * NHEAD * NT) * sizeof(float), stream);

  // attention partials -> Oacc/lacc (3456 balanced 8-tile chunk-blocks)
  attn<<<dim3(144, NHEAD, NB), 256, 0, stream>>>(qkvb, vTb, Oacc, lacc);

  // normalize -> bf16 aob
  finalize<<<(MTOK * NC / 4 + 255) / 256, 256, 0, stream>>>(Oacc, lacc, aob);

  // out = att_out @ w_proj -> fp32 d_out
  gemm128<0><<<dim3(NC / 128, MTOK / 128), 256, 0, stream>>>(aob, wpT, outp, nullptr, MTOK, NC, NC);
}

// Round 2
// 311.024 us; speedup vs baseline: 1.0088x; 1.0088x over previous
//
#include <hip/hip_runtime.h>
#include <hip/hip_bf16.h>
#include <stdint.h>

// Problem constants
#define NB 2
#define NT 4096
#define NC 768
#define NHEAD 12
#define HS 64
#define MTOK (NB * NT)      // 8192
#define C3 (3 * NC)         // 2304

typedef __bf16 bf16x8 __attribute__((ext_vector_type(8)));
typedef float f32x4 __attribute__((ext_vector_type(4)));
typedef float f32x16 __attribute__((ext_vector_type(16)));

#define KSCALE_LOG2E 0.18033688011f   // (1/sqrt(64)) * log2(e)

__device__ __forceinline__ unsigned short f2bf(float f) {  // RNE
  union { float f; uint32_t u; } v; v.f = f;
  uint32_t r = v.u + 0x7fffu + ((v.u >> 16) & 1u);
  return (unsigned short)(r >> 16);
}
__device__ __forceinline__ unsigned short bft(float f) {   // truncate
  return (unsigned short)(__builtin_bit_cast(unsigned int, f) >> 16);
}
// pack two floats as truncated bf16 pair: low short = a, high short = b
__device__ __forceinline__ uint32_t pack_bf2(float a, float b) {
  return (__builtin_bit_cast(uint32_t, b) & 0xffff0000u) |
         (__builtin_bit_cast(uint32_t, a) >> 16);
}

// async global->LDS, 16B per lane: lane i lands at ldsbase + i*16B.
__device__ __forceinline__ void gload_lds16(const unsigned short* g, unsigned short* ldsbase) {
  __builtin_amdgcn_global_load_lds(
      (const __attribute__((address_space(1))) unsigned int*)g,
      (__attribute__((address_space(3))) unsigned int*)ldsbase, 16, 0, 0);
}

__device__ __forceinline__ f32x4 mfma16(bf16x8 a, bf16x8 b, f32x4 c) {
  return __builtin_amdgcn_mfma_f32_16x16x32_bf16(a, b, c, 0, 0, 0);
}
__device__ __forceinline__ f32x16 mfma32(bf16x8 a, bf16x8 b, f32x16 c) {
  return __builtin_amdgcn_mfma_f32_32x32x16_bf16(a, b, c, 0, 0, 0);
}

// ---------------- prep: coalesced LDS-tiled transposes + x cast ----------------
__global__ __launch_bounds__(256) void prep(
    const float* __restrict__ x, const float* __restrict__ wa, const float* __restrict__ wp,
    unsigned short* __restrict__ xb, unsigned short* __restrict__ waT,
    unsigned short* __restrict__ wpT) {
  const int bx = blockIdx.x;
  if (bx < 576) {
    __shared__ float tile[64][65];
    const float* src; unsigned short* dst;
    int srcN, dstN, k0, n0, qscale;
    if (bx < 432) {
      src = wa; dst = waT; srcN = C3; dstN = NC; qscale = 1;
      k0 = (bx / 36) * 64; n0 = (bx % 36) * 64;
    } else {
      const int t = bx - 432;
      src = wp; dst = wpT; srcN = NC; dstN = NC; qscale = 0;
      k0 = (t / 12) * 64; n0 = (t % 12) * 64;
    }
    const int tr = threadIdx.x >> 4;        // 0..15
    const int tc = (threadIdx.x & 15) * 4;  // 0,4,..,60
#pragma unroll
    for (int p = 0; p < 4; ++p) {
      const int r = p * 16 + tr;
      const float4 v = *reinterpret_cast<const float4*>(src + (size_t)(k0 + r) * srcN + n0 + tc);
      tile[r][tc + 0] = v.x; tile[r][tc + 1] = v.y;
      tile[r][tc + 2] = v.z; tile[r][tc + 3] = v.w;
    }
    __syncthreads();
#pragma unroll
    for (int p = 0; p < 4; ++p) {
      const int n = p * 16 + tr;   // output row = source column n0+n
      const float sc = (qscale && (n0 + n) < NC) ? KSCALE_LOG2E : 1.0f;
      ushort4 o;
      o.x = f2bf(tile[tc + 0][n] * sc); o.y = f2bf(tile[tc + 1][n] * sc);
      o.z = f2bf(tile[tc + 2][n] * sc); o.w = f2bf(tile[tc + 3][n] * sc);
      *reinterpret_cast<ushort4*>(dst + (size_t)(n0 + n) * dstN + k0 + tc) = o;
    }
  } else {
    const int gid = (bx - 576) * 256 + threadIdx.x;   // < MTOK*NC/4
    const float4 v = reinterpret_cast<const float4*>(x)[gid];
    ushort4 o;
    o.x = f2bf(v.x); o.y = f2bf(v.y); o.z = f2bf(v.z); o.w = f2bf(v.w);
    reinterpret_cast<ushort4*>(xb)[gid] = o;
  }
}

// ---------------- GEMM 128x128: C[M,N] = A[M,K] @ Bt[N,K]^T ----------------
// OUT_BF16=1 (gemm1): blocks with col0 >= 2*NC hold the V tile -> transpose
// in-block via smem (16B-chunk XOR swizzle) and write straight to vT
// [B*NH][HS][T]; qkvb's V slice is never written. Other blocks write qkvb rows.
template <int OUT_BF16>
__global__ __launch_bounds__(256) void gemm128(
    const unsigned short* __restrict__ A,   // [M][K]
    const unsigned short* __restrict__ Bt,  // [N][K]
    void* __restrict__ Cout,
    unsigned short* __restrict__ vT,        // used only by OUT_BF16 V-blocks
    int M, int N, int K) {
  __shared__ unsigned short smem[2 * 128 * 64];
  unsigned short* As = smem;
  unsigned short* Bs = smem + 128 * 64;

  const int tid = threadIdx.x;
  const int wave = tid >> 6;
  const int lane = tid & 63;
  const int li = lane & 15;
  const int lq = lane >> 4;
  const int wm = wave & 1;
  const int wn = wave >> 1;
  const int row0 = blockIdx.y * 128;
  const int col0 = blockIdx.x * 128;

  const int crow = lane >> 3;
  const int cchunk = ((lane & 7) ^ crow) * 8;

  f32x4 acc[4][4] = {};

  for (int k0 = 0; k0 < K; k0 += 64) {
#pragma unroll
    for (int i = 0; i < 4; ++i) {
      const int R = wave * 32 + i * 8;
      gload_lds16(A + (size_t)(row0 + R + crow) * K + k0 + cchunk, &As[R * 64]);
      gload_lds16(Bt + (size_t)(col0 + R + crow) * K + k0 + cchunk, &Bs[R * 64]);
    }
    __syncthreads();

#pragma unroll
    for (int ks = 0; ks < 2; ++ks) {
      bf16x8 af[4], bf[4];
#pragma unroll
      for (int f = 0; f < 4; ++f) {
        const int arow = wm * 64 + f * 16 + li;
        af[f] = *reinterpret_cast<const bf16x8*>(&As[arow * 64 + (((ks * 4 + lq) ^ (li & 7)) << 3)]);
        const int brow = wn * 64 + f * 16 + li;
        bf[f] = *reinterpret_cast<const bf16x8*>(&Bs[brow * 64 + (((ks * 4 + lq) ^ (li & 7)) << 3)]);
      }
#pragma unroll
      for (int fa = 0; fa < 4; ++fa)
#pragma unroll
        for (int fb = 0; fb < 4; ++fb)
          acc[fa][fb] = mfma16(af[fa], bf[fb], acc[fa][fb]);
    }
    __syncthreads();   // also protects smem reuse in the fused epilogue
  }

  if (OUT_BF16) {
    if (col0 >= 2 * NC) {
      // ---- fused V transpose: acc -> smem[c][t] -> vT[bh][d][t] ----
      const int b = row0 >> 12;            // row0 / NT
      const int t0r = row0 & (NT - 1);
      const int h0 = (col0 - 2 * NC) >> 6;
      // write phase: value at (c = head-col, t = token) with 16B-chunk XOR swizzle
#pragma unroll
      for (int fa = 0; fa < 4; ++fa) {
#pragma unroll
        for (int fb = 0; fb < 4; ++fb) {
          const int cc = wn * 64 + fb * 16 + li;
#pragma unroll
          for (int r = 0; r < 4; ++r) {
            const int tt = wm * 64 + fa * 16 + lq * 4 + r;
            const int slot = cc * 16 + ((tt >> 3) ^ (cc & 15));
            smem[slot * 8 + (tt & 7)] = f2bf(acc[fa][fb][r]);
          }
        }
      }
      __syncthreads();
      // read phase: 16 lanes cover one c-row's 16 chunks -> 256B coalesced stores
      const int ch = tid & 15;
#pragma unroll
      for (int j = 0; j < 8; ++j) {
        const int cc = (tid >> 4) + 16 * j;
        const uint4 v = *reinterpret_cast<const uint4*>(
            smem + (size_t)(cc * 16 + (ch ^ (cc & 15))) * 8);
        const int bh = b * NHEAD + h0 + (cc >> 6);
        const int d = cc & 63;
        *reinterpret_cast<uint4*>(vT + (size_t)bh * HS * NT + (size_t)d * NT + t0r + ch * 8) = v;
      }
    } else {
      unsigned short* Cb = (unsigned short*)Cout;
#pragma unroll
      for (int fa = 0; fa < 4; ++fa) {
        const int gr = row0 + wm * 64 + fa * 16 + lq * 4;
#pragma unroll
        for (int fb = 0; fb < 4; ++fb) {
          const int gc = col0 + wn * 64 + fb * 16 + li;
#pragma unroll
          for (int r = 0; r < 4; ++r)
            Cb[(size_t)(gr + r) * N + gc] = f2bf(acc[fa][fb][r]);
        }
      }
    }
  } else {
    float* Cf = (float*)Cout;
#pragma unroll
    for (int fa = 0; fa < 4; ++fa) {
      const int gr = row0 + wm * 64 + fa * 16 + lq * 4;
#pragma unroll
      for (int fb = 0; fb < 4; ++fb) {
        const int gc = col0 + wn * 64 + fb * 16 + li;
#pragma unroll
        for (int r = 0; r < 4; ++r)
          Cf[(size_t)(gr + r) * N + gc] = acc[fa][fb][r];
      }
    }
  }
}

// ---------------- Flash attention: 32x32 swapped QK^T, P in registers ----------------
// Structure: 4 waves x 32 q-rows = 128 q per block; KV tile 64; balanced
// split-KV chunks (<=8 tiles, 144 per (b,h), grid 3456) as before.
// S^T = mfma32(K_frag(A), Q_frag(B)): C-layout col=lane&31 = q, row = k-token
// = (reg&3)+8*(reg>>2)+4*(lane>>5). Each lane owns ONE q-column -> exp fully
// in-register, P rebuilt as PV A-fragment via pack_bf2 + v_permlane32_swap_b32
// (16 packs + 8 swaps per tile). No P LDS buffer, no mid-tile lgkmcnt, LDS
// back to 32KB. l-row-sums on the MFMA pipe via mfma32(P, ones).
// Per-wave causal skip: kblk active iff t0 + kblk*32 <= qw+31 (wave-uniform).

__global__ __launch_bounds__(256) void attn(
    const unsigned short* __restrict__ qkv,   // [B][T][3C] (V slice unused)
    const unsigned short* __restrict__ vT,    // [B*NH][HS][T]
    float* __restrict__ Oacc,                 // [MTOK][NC] fp32, zeroed
    float* __restrict__ lacc) {               // [B*NH][NT]  fp32, zeroed
  __shared__ unsigned short Ks[2][64 * 64];
  __shared__ unsigned short Vts[2][64 * 64];

  const int tid = threadIdx.x;
  const int wave = tid >> 6;
  const int lane = tid & 63;
  const int l31 = lane & 31;
  const int lh = lane >> 5;
  const int sw = l31 & 7;                     // XOR-swizzle key for frag reads

  // ---- chunk decode: c in [0,144) -> (q-tile qi, chunk ck) ----
  const int c = 143 - (int)blockIdx.x;
  int g = 0;
#pragma unroll
  for (int gg = 1; gg < 8; ++gg)
    if (2 * gg * (gg + 1) <= c) g = gg;       // group g: q-tiles 4g..4g+3, g+1 chunks each
  const int rem = c - 2 * g * (g + 1);
  const int dq = rem / (g + 1);
  const int qi = 4 * g + dq;                  // q-tile 0..31
  const int ck = rem - dq * (g + 1);          // chunk 0..g
  const int q0 = qi * 128;
  const int ntile = 2 * qi + 2;
  const int tauS = ck * 8;
  const int tauE = (tauS + 8 < ntile) ? tauS + 8 : ntile;

  const int h = blockIdx.y;
  const int b = blockIdx.z;
  const int bh = b * NHEAD + h;

  const size_t baseQ = (size_t)b * NT * C3 + (size_t)h * HS;
  const size_t baseK = baseQ + NC;
  const unsigned short* kq = qkv + baseK;
  const unsigned short* vbase = vT + (size_t)bh * HS * NT;

  const int qw = q0 + wave * 32;              // wave's first q row
  const int qtok = qw + l31;                  // this lane's q token

  // Q B-fragments (pre-scaled via waT): lane holds Q[q=qw+l31][ks*16+lh*8..+7]
  bf16x8 bq[4];
#pragma unroll
  for (int ks = 0; ks < 4; ++ks)
    bq[ks] = *reinterpret_cast<const bf16x8*>(
        qkv + baseQ + (size_t)(qw + l31) * C3 + ks * 16 + lh * 8);

  // all-ones B fragment for l row-sums on the MFMA pipe
  bf16x8 vones;
#pragma unroll
  for (int i = 0; i < 8; ++i) vones[i] = (__bf16)1.0f;

  f32x16 o0 = {}, o1 = {}, la = {};

  // ---- gload staging geometry: per wave, 2 calls x 8 rows for K and V ----
  // DMA writes linear (wave-uniform LDS base + lane*16B); the XOR swizzle is
  // applied on the per-lane GLOBAL address instead: LDS[R][c] = G[R][c^(R&7)].
  const int grow = lane >> 3;               // row within 8-row group
  const int gch = (lane & 7) ^ grow;        // pre-swizzled 16B chunk
  const int wr0 = wave * 8;                 // uniform row bases
  const int wr1 = wave * 8 + 32;

#define STAGE(TAU, BUFI)                                                        \
  do {                                                                          \
    const int t0s_ = (TAU) * 64;                                                \
    gload_lds16(kq + (size_t)(t0s_ + wr0 + grow) * C3 + gch * 8,                \
                &Ks[BUFI][wr0 * 64]);                                           \
    gload_lds16(kq + (size_t)(t0s_ + wr1 + grow) * C3 + gch * 8,                \
                &Ks[BUFI][wr1 * 64]);                                           \
    gload_lds16(vbase + (size_t)(wr0 + grow) * NT + t0s_ + gch * 8,             \
                &Vts[BUFI][wr0 * 64]);                                          \
    gload_lds16(vbase + (size_t)(wr1 + grow) * NT + t0s_ + gch * 8,             \
                &Vts[BUFI][wr1 * 64]);                                          \
  } while (0)

// exp + pack + permlane-swap one 32-k block (16 S^T regs) into pa[2*KBLK+s].
// k-token of reg r = KB + (r&3) + 8*(r>>2)  (KB already includes +4*lh).
#define EXP_PACK(ST, KBLK, DOMASK)                                             \
  do {                                                                         \
    const int kb_ = t0 + (KBLK) * 32 + 4 * lh;                                 \
    float p_[16];                                                              \
    _Pragma("unroll") for (int r = 0; r < 16; ++r) {                           \
      float v_ = (ST)[r];                                                      \
      if (DOMASK) {                                                            \
        const int kt_ = kb_ + (r & 3) + 8 * (r >> 2);                          \
        if (kt_ > qtok) v_ = -INFINITY;                                        \
      }                                                                        \
      p_[r] = __builtin_amdgcn_exp2f(v_);                                      \
    }                                                                          \
    _Pragma("unroll") for (int s = 0; s < 2; ++s) {                            \
      uint32_t a_ = pack_bf2(p_[8 * s + 0], p_[8 * s + 1]);                    \
      uint32_t b_ = pack_bf2(p_[8 * s + 2], p_[8 * s + 3]);                    \
      uint32_t c_ = pack_bf2(p_[8 * s + 4], p_[8 * s + 5]);                    \
      uint32_t d_ = pack_bf2(p_[8 * s + 6], p_[8 * s + 7]);                    \
      asm("v_permlane32_swap_b32 %0, %1" : "+v"(a_), "+v"(c_));                \
      asm("v_permlane32_swap_b32 %0, %1" : "+v"(b_), "+v"(d_));                \
      union { uint32_t u[4]; bf16x8 v8; } pu_;                                 \
      pu_.u[0] = a_; pu_.u[1] = b_; pu_.u[2] = c_; pu_.u[3] = d_;              \
      pa[2 * (KBLK) + s] = pu_.v8;                                             \
    }                                                                          \
  } while (0)

// one PV k-step (16 k-tokens): l += P.1 ; O += P V  (V B-frag rows = d)
#define PV_STEP(KS)                                                            \
  do {                                                                         \
    const int off_ = ((((KS) * 2 + lh) ^ sw) << 3);                            \
    const bf16x8 bv0_ =                                                        \
        *reinterpret_cast<const bf16x8*>(Vc + (size_t)l31 * 64 + off_);        \
    const bf16x8 bv1_ =                                                        \
        *reinterpret_cast<const bf16x8*>(Vc + (size_t)(32 + l31) * 64 + off_); \
    la = mfma32(pa[KS], vones, la);                                            \
    o0 = mfma32(pa[KS], bv0_, o0);                                             \
    o1 = mfma32(pa[KS], bv1_, o1);                                             \
  } while (0)

  STAGE(tauS, 0);

  int cur = 0;
  for (int tau = tauS; tau < tauE; ++tau) {
    const int t0 = tau * 64;
    // implicit vmcnt(0)+lgkmcnt(0) drain: publishes buf[cur] DMA writes and
    // guarantees prior tile's LDS reads are done before next STAGE overwrite.
    __syncthreads();
    if (tau + 1 < tauE) STAGE(tau + 1, cur ^ 1);

    const unsigned short* Kc = Ks[cur];
    const unsigned short* Vc = Vts[cur];

    if (t0 <= qw + 31) {                 // wave has live q-rows in this tile
      const bool act1 = (t0 + 32 <= qw + 31);   // k-block 1 live?
      const bool m0 = (t0 + 31 > qw);           // k-block 0 needs masking?
      const bool m1 = (t0 + 63 > qw);           // k-block 1 needs masking?

      // ---- S^T = K Q^T: A = K rows (k-tokens), B = Q cols ----
      f32x16 st0 = {}, st1 = {};
      __builtin_amdgcn_s_setprio(1);
#pragma unroll
      for (int ks = 0; ks < 4; ++ks) {
        const bf16x8 ka = *reinterpret_cast<const bf16x8*>(
            Kc + (size_t)l31 * 64 + (((ks * 2 + lh) ^ sw) << 3));
        st0 = mfma32(ka, bq[ks], st0);
      }
      if (act1) {
#pragma unroll
        for (int ks = 0; ks < 4; ++ks) {
          const bf16x8 ka = *reinterpret_cast<const bf16x8*>(
              Kc + (size_t)(32 + l31) * 64 + (((ks * 2 + lh) ^ sw) << 3));
          st1 = mfma32(ka, bq[ks], st1);
        }
      }
      __builtin_amdgcn_s_setprio(0);

      // ---- exp + pack + swap -> pa[4] (in-register P, bf16 truncate) ----
      bf16x8 pa[4];
      EXP_PACK(st0, 0, m0);
      if (act1) EXP_PACK(st1, 1, m1);

      // ---- O += P V ; l += P . ones (MFMA pipe) ----
      __builtin_amdgcn_s_setprio(1);
      PV_STEP(0); PV_STEP(1);
      if (act1) { PV_STEP(2); PV_STEP(3); }
      __builtin_amdgcn_s_setprio(0);
    }
    cur ^= 1;
  }
#undef STAGE
#undef EXP_PACK
#undef PV_STEP

  // ---- atomic partial accumulation (unnormalized; la uniform across l31) ----
  const size_t obase = (size_t)b * NT * NC + (size_t)h * HS;
  float* lrow = lacc + (size_t)bh * NT;
#pragma unroll
  for (int r = 0; r < 16; ++r) {
    const int q = qw + (r & 3) + 8 * (r >> 2) + 4 * lh;
    if (l31 == 0) atomicAdd(&lrow[q], la[r]);
    atomicAdd(&Oacc[obase + (size_t)q * NC + l31], o0[r]);
    atomicAdd(&Oacc[obase + (size_t)q * NC + 32 + l31], o1[r]);
  }
}

// ---------------- finalize: aob = bf16(Oacc / l) ----------------
__global__ __launch_bounds__(256) void finalize(
    const float* __restrict__ Oacc, const float* __restrict__ lacc,
    unsigned short* __restrict__ aob) {
  const int idx4 = (blockIdx.x * 256 + threadIdx.x);
  if (idx4 >= MTOK * NC / 4) return;
  const int idx = idx4 * 4;
  const int row = idx / NC;
  const int cc = idx - row * NC;
  const int h = cc >> 6;
  const int b = row >> 12;            // NT = 4096
  const int t = row & (NT - 1);
  const float inv = 1.0f / lacc[(size_t)(b * NHEAD + h) * NT + t];
  const float4 v = reinterpret_cast<const float4*>(Oacc)[idx4];
  ushort4 o;
  o.x = bft(v.x * inv); o.y = bft(v.y * inv);
  o.z = bft(v.z * inv); o.w = bft(v.w * inv);
  reinterpret_cast<ushort4*>(aob)[idx4] = o;
}

// ---------------- launch ----------------
extern "C" void kernel_launch(void* const* d_in, const int* in_sizes, int n_in,
                              void* d_out, int out_size, void* d_ws, size_t ws_size,
                              hipStream_t stream) {
  const float* x = (const float*)d_in[0];       // [B,T,C]
  const float* w_attn = (const float*)d_in[1];  // [C, 3C]
  const float* w_proj = (const float*)d_in[2];  // [C, C]
  float* outp = (float*)d_out;

  // ws layout (Oacc aliases xb/waT, which die after gemm1):
  char* w = (char*)d_ws;
  float* Oacc = (float*)w;
  unsigned short* xb = (unsigned short*)w;                       // aliases Oacc (pre-attn)
  unsigned short* waT = xb + (size_t)MTOK * NC;                  // aliases Oacc tail
  float* lacc = Oacc + (size_t)MTOK * NC;
  unsigned short* qkvb = (unsigned short*)(lacc + (size_t)NB * NHEAD * NT);
  unsigned short* aob  = qkvb + (size_t)MTOK * C3;               // [MTOK][NC] bf16
  unsigned short* vTb  = aob + (size_t)MTOK * NC;                // [B*NH][HS][T]
  unsigned short* wpT  = vTb + (size_t)MTOK * NC;                // [NC][NC] bf16

  // prep: 576 transpose tiles + x-cast blocks
  prep<<<576 + MTOK * NC / 4 / 256, 256, 0, stream>>>(x, w_attn, w_proj, xb, waT, wpT);

  // qkv = x @ w_attn (Q rows of waT pre-scaled); V blocks write vTb directly
  gemm128<1><<<dim3(C3 / 128, MTOK / 128), 256, 0, stream>>>(xb, waT, qkvb, vTb, MTOK, C3, NC);

  // zero partial accumulators (xb/waT now dead)
  hipMemsetAsync(Oacc, 0, ((size_t)MTOK * NC + (size_t)NB * NHEAD * NT) * sizeof(float), stream);

  // attention partials -> Oacc/lacc (3456 balanced 8-tile chunk-blocks)
  attn<<<dim3(144, NHEAD, NB), 256, 0, stream>>>(qkvb, vTb, Oacc, lacc);

  // normalize -> bf16 aob
  finalize<<<(MTOK * NC / 4 + 255) / 256, 256, 0, stream>>>(Oacc, lacc, aob);

  // out = att_out @ w_proj -> fp32 d_out
  gemm128<0><<<dim3(NC / 128, MTOK / 128), 256, 0, stream>>>(aob, wpT, outp, nullptr, MTOK, NC, NC);
}

// Round 3
// 293.290 us; speedup vs baseline: 1.0698x; 1.0605x over previous
//
#include <hip/hip_runtime.h>
#include <hip/hip_bf16.h>
#include <stdint.h>

// Problem constants
#define NB 2
#define NT 4096
#define NC 768
#define NHEAD 12
#define HS 64
#define MTOK (NB * NT)      // 8192
#define C3 (3 * NC)         // 2304

typedef __bf16 bf16x8 __attribute__((ext_vector_type(8)));
typedef float f32x4 __attribute__((ext_vector_type(4)));
typedef float f32x16 __attribute__((ext_vector_type(16)));

#define KSCALE_LOG2E 0.18033688011f   // (1/sqrt(64)) * log2(e)

__device__ __forceinline__ unsigned short f2bf(float f) {  // RNE
  union { float f; uint32_t u; } v; v.f = f;
  uint32_t r = v.u + 0x7fffu + ((v.u >> 16) & 1u);
  return (unsigned short)(r >> 16);
}
__device__ __forceinline__ unsigned short bft(float f) {   // truncate
  return (unsigned short)(__builtin_bit_cast(unsigned int, f) >> 16);
}
// pack two floats as truncated bf16 pair: low short = a, high short = b
__device__ __forceinline__ uint32_t pack_bf2(float a, float b) {
  return (__builtin_bit_cast(uint32_t, b) & 0xffff0000u) |
         (__builtin_bit_cast(uint32_t, a) >> 16);
}

// async global->LDS, 16B per lane: lane i lands at ldsbase + i*16B.
__device__ __forceinline__ void gload_lds16(const unsigned short* g, unsigned short* ldsbase) {
  __builtin_amdgcn_global_load_lds(
      (const __attribute__((address_space(1))) unsigned int*)g,
      (__attribute__((address_space(3))) unsigned int*)ldsbase, 16, 0, 0);
}

__device__ __forceinline__ f32x4 mfma16(bf16x8 a, bf16x8 b, f32x4 c) {
  return __builtin_amdgcn_mfma_f32_16x16x32_bf16(a, b, c, 0, 0, 0);
}
__device__ __forceinline__ f32x16 mfma32(bf16x8 a, bf16x8 b, f32x16 c) {
  return __builtin_amdgcn_mfma_f32_32x32x16_bf16(a, b, c, 0, 0, 0);
}

// ---------------- prep: coalesced LDS-tiled transposes + x cast ----------------
__global__ __launch_bounds__(256) void prep(
    const float* __restrict__ x, const float* __restrict__ wa, const float* __restrict__ wp,
    unsigned short* __restrict__ xb, unsigned short* __restrict__ waT,
    unsigned short* __restrict__ wpT) {
  const int bx = blockIdx.x;
  if (bx < 576) {
    __shared__ float tile[64][65];
    const float* src; unsigned short* dst;
    int srcN, dstN, k0, n0, qscale;
    if (bx < 432) {
      src = wa; dst = waT; srcN = C3; dstN = NC; qscale = 1;
      k0 = (bx / 36) * 64; n0 = (bx % 36) * 64;
    } else {
      const int t = bx - 432;
      src = wp; dst = wpT; srcN = NC; dstN = NC; qscale = 0;
      k0 = (t / 12) * 64; n0 = (t % 12) * 64;
    }
    const int tr = threadIdx.x >> 4;        // 0..15
    const int tc = (threadIdx.x & 15) * 4;  // 0,4,..,60
#pragma unroll
    for (int p = 0; p < 4; ++p) {
      const int r = p * 16 + tr;
      const float4 v = *reinterpret_cast<const float4*>(src + (size_t)(k0 + r) * srcN + n0 + tc);
      tile[r][tc + 0] = v.x; tile[r][tc + 1] = v.y;
      tile[r][tc + 2] = v.z; tile[r][tc + 3] = v.w;
    }
    __syncthreads();
#pragma unroll
    for (int p = 0; p < 4; ++p) {
      const int n = p * 16 + tr;   // output row = source column n0+n
      const float sc = (qscale && (n0 + n) < NC) ? KSCALE_LOG2E : 1.0f;
      ushort4 o;
      o.x = f2bf(tile[tc + 0][n] * sc); o.y = f2bf(tile[tc + 1][n] * sc);
      o.z = f2bf(tile[tc + 2][n] * sc); o.w = f2bf(tile[tc + 3][n] * sc);
      *reinterpret_cast<ushort4*>(dst + (size_t)(n0 + n) * dstN + k0 + tc) = o;
    }
  } else {
    const int gid = (bx - 576) * 256 + threadIdx.x;   // < MTOK*NC/4
    const float4 v = reinterpret_cast<const float4*>(x)[gid];
    ushort4 o;
    o.x = f2bf(v.x); o.y = f2bf(v.y); o.z = f2bf(v.z); o.w = f2bf(v.w);
    reinterpret_cast<ushort4*>(xb)[gid] = o;
  }
}

// ---------------- GEMM 128x128: C[M,N] = A[M,K] @ Bt[N,K]^T ----------------
// OUT_BF16=1 (gemm1): blocks with col0 >= 2*NC hold the V tile -> transpose
// in-block via smem (16B-chunk XOR swizzle) and write straight to vT
// [B*NH][HS][T]; qkvb's V slice is never written. Other blocks write qkvb rows.
template <int OUT_BF16>
__global__ __launch_bounds__(256) void gemm128(
    const unsigned short* __restrict__ A,   // [M][K]
    const unsigned short* __restrict__ Bt,  // [N][K]
    void* __restrict__ Cout,
    unsigned short* __restrict__ vT,        // used only by OUT_BF16 V-blocks
    int M, int N, int K) {
  __shared__ unsigned short smem[2 * 128 * 64];
  unsigned short* As = smem;
  unsigned short* Bs = smem + 128 * 64;

  const int tid = threadIdx.x;
  const int wave = tid >> 6;
  const int lane = tid & 63;
  const int li = lane & 15;
  const int lq = lane >> 4;
  const int wm = wave & 1;
  const int wn = wave >> 1;
  const int row0 = blockIdx.y * 128;
  const int col0 = blockIdx.x * 128;

  const int crow = lane >> 3;
  const int cchunk = ((lane & 7) ^ crow) * 8;

  f32x4 acc[4][4] = {};

  for (int k0 = 0; k0 < K; k0 += 64) {
#pragma unroll
    for (int i = 0; i < 4; ++i) {
      const int R = wave * 32 + i * 8;
      gload_lds16(A + (size_t)(row0 + R + crow) * K + k0 + cchunk, &As[R * 64]);
      gload_lds16(Bt + (size_t)(col0 + R + crow) * K + k0 + cchunk, &Bs[R * 64]);
    }
    __syncthreads();

#pragma unroll
    for (int ks = 0; ks < 2; ++ks) {
      bf16x8 af[4], bf[4];
#pragma unroll
      for (int f = 0; f < 4; ++f) {
        const int arow = wm * 64 + f * 16 + li;
        af[f] = *reinterpret_cast<const bf16x8*>(&As[arow * 64 + (((ks * 4 + lq) ^ (li & 7)) << 3)]);
        const int brow = wn * 64 + f * 16 + li;
        bf[f] = *reinterpret_cast<const bf16x8*>(&Bs[brow * 64 + (((ks * 4 + lq) ^ (li & 7)) << 3)]);
      }
#pragma unroll
      for (int fa = 0; fa < 4; ++fa)
#pragma unroll
        for (int fb = 0; fb < 4; ++fb)
          acc[fa][fb] = mfma16(af[fa], bf[fb], acc[fa][fb]);
    }
    __syncthreads();   // also protects smem reuse in the fused epilogue
  }

  if (OUT_BF16) {
    if (col0 >= 2 * NC) {
      // ---- fused V transpose: acc -> smem[c][t] -> vT[bh][d][t] ----
      const int b = row0 >> 12;            // row0 / NT
      const int t0r = row0 & (NT - 1);
      const int h0 = (col0 - 2 * NC) >> 6;
      // write phase: value at (c = head-col, t = token) with 16B-chunk XOR swizzle
#pragma unroll
      for (int fa = 0; fa < 4; ++fa) {
#pragma unroll
        for (int fb = 0; fb < 4; ++fb) {
          const int cc = wn * 64 + fb * 16 + li;
#pragma unroll
          for (int r = 0; r < 4; ++r) {
            const int tt = wm * 64 + fa * 16 + lq * 4 + r;
            const int slot = cc * 16 + ((tt >> 3) ^ (cc & 15));
            smem[slot * 8 + (tt & 7)] = f2bf(acc[fa][fb][r]);
          }
        }
      }
      __syncthreads();
      // read phase: 16 lanes cover one c-row's 16 chunks -> 256B coalesced stores
      const int ch = tid & 15;
#pragma unroll
      for (int j = 0; j < 8; ++j) {
        const int cc = (tid >> 4) + 16 * j;
        const uint4 v = *reinterpret_cast<const uint4*>(
            smem + (size_t)(cc * 16 + (ch ^ (cc & 15))) * 8);
        const int bh = b * NHEAD + h0 + (cc >> 6);
        const int d = cc & 63;
        *reinterpret_cast<uint4*>(vT + (size_t)bh * HS * NT + (size_t)d * NT + t0r + ch * 8) = v;
      }
    } else {
      unsigned short* Cb = (unsigned short*)Cout;
#pragma unroll
      for (int fa = 0; fa < 4; ++fa) {
        const int gr = row0 + wm * 64 + fa * 16 + lq * 4;
#pragma unroll
        for (int fb = 0; fb < 4; ++fb) {
          const int gc = col0 + wn * 64 + fb * 16 + li;
#pragma unroll
          for (int r = 0; r < 4; ++r)
            Cb[(size_t)(gr + r) * N + gc] = f2bf(acc[fa][fb][r]);
        }
      }
    }
  } else {
    float* Cf = (float*)Cout;
#pragma unroll
    for (int fa = 0; fa < 4; ++fa) {
      const int gr = row0 + wm * 64 + fa * 16 + lq * 4;
#pragma unroll
      for (int fb = 0; fb < 4; ++fb) {
        const int gc = col0 + wn * 64 + fb * 16 + li;
#pragma unroll
        for (int r = 0; r < 4; ++r)
          Cf[(size_t)(gr + r) * N + gc] = acc[fa][fb][r];
      }
    }
  }
}

// ---------------- Flash attention: owner-block per q-tile, no atomics ----------------
// One block owns q-tile qi (128 q rows, 4 waves x 32); iterates ALL its
// 2qi+2 KV tiles, accumulating O and l in registers, then normalizes
// in-register and stores bf16 directly to aob. No Oacc/lacc, no memset, no
// finalize. Grid dim3(32,12,2), qi = 31 - blockIdx.x so largest triangles
// dispatch first (short qi~0 blocks fill the tail).
// Inner tile: dbuf K/V via global_load_lds (pre-swizzled global source,
// linear LDS dest), one barrier/tile; S^T = mfma32(K_frag, Q_frag) so each
// lane owns one q-column; exp fully in-register; P rebuilt as PV A-fragment
// via pack_bf2 + v_permlane32_swap_b32; l row-sums on the MFMA pipe.

__global__ __launch_bounds__(256) void attn(
    const unsigned short* __restrict__ qkv,   // [B][T][3C] (V slice unused)
    const unsigned short* __restrict__ vT,    // [B*NH][HS][T]
    unsigned short* __restrict__ aob) {       // [MTOK][NC] bf16 out
  __shared__ unsigned short Ks[2][64 * 64];
  __shared__ unsigned short Vts[2][64 * 64];

  const int tid = threadIdx.x;
  const int wave = tid >> 6;
  const int lane = tid & 63;
  const int l31 = lane & 31;
  const int lh = lane >> 5;
  const int sw = l31 & 7;                     // XOR-swizzle key for frag reads

  const int qi = 31 - (int)blockIdx.x;        // largest first
  const int q0 = qi * 128;
  const int ntile = 2 * qi + 2;

  const int h = blockIdx.y;
  const int b = blockIdx.z;
  const int bh = b * NHEAD + h;

  const size_t baseQ = (size_t)b * NT * C3 + (size_t)h * HS;
  const size_t baseK = baseQ + NC;
  const unsigned short* kq = qkv + baseK;
  const unsigned short* vbase = vT + (size_t)bh * HS * NT;

  const int qw = q0 + wave * 32;              // wave's first q row
  const int qtok = qw + l31;                  // this lane's q token

  // Q B-fragments (pre-scaled via waT): lane holds Q[q=qw+l31][ks*16+lh*8..+7]
  bf16x8 bq[4];
#pragma unroll
  for (int ks = 0; ks < 4; ++ks)
    bq[ks] = *reinterpret_cast<const bf16x8*>(
        qkv + baseQ + (size_t)(qw + l31) * C3 + ks * 16 + lh * 8);

  // all-ones B fragment for l row-sums on the MFMA pipe
  bf16x8 vones;
#pragma unroll
  for (int i = 0; i < 8; ++i) vones[i] = (__bf16)1.0f;

  f32x16 o0 = {}, o1 = {}, la = {};

  // ---- gload staging geometry: per wave, 2 calls x 8 rows for K and V ----
  // DMA writes linear (wave-uniform LDS base + lane*16B); the XOR swizzle is
  // applied on the per-lane GLOBAL address instead: LDS[R][c] = G[R][c^(R&7)].
  const int grow = lane >> 3;               // row within 8-row group
  const int gch = (lane & 7) ^ grow;        // pre-swizzled 16B chunk
  const int wr0 = wave * 8;                 // uniform row bases
  const int wr1 = wave * 8 + 32;

#define STAGE(TAU, BUFI)                                                        \
  do {                                                                          \
    const int t0s_ = (TAU) * 64;                                                \
    gload_lds16(kq + (size_t)(t0s_ + wr0 + grow) * C3 + gch * 8,                \
                &Ks[BUFI][wr0 * 64]);                                           \
    gload_lds16(kq + (size_t)(t0s_ + wr1 + grow) * C3 + gch * 8,                \
                &Ks[BUFI][wr1 * 64]);                                           \
    gload_lds16(vbase + (size_t)(wr0 + grow) * NT + t0s_ + gch * 8,             \
                &Vts[BUFI][wr0 * 64]);                                          \
    gload_lds16(vbase + (size_t)(wr1 + grow) * NT + t0s_ + gch * 8,             \
                &Vts[BUFI][wr1 * 64]);                                          \
  } while (0)

// exp + pack + permlane-swap one 32-k block (16 S^T regs) into pa[2*KBLK+s].
// k-token of reg r = KB + (r&3) + 8*(r>>2)  (KB already includes +4*lh).
#define EXP_PACK(ST, KBLK, DOMASK)                                             \
  do {                                                                         \
    const int kb_ = t0 + (KBLK) * 32 + 4 * lh;                                 \
    float p_[16];                                                              \
    _Pragma("unroll") for (int r = 0; r < 16; ++r) {                           \
      float v_ = (ST)[r];                                                      \
      if (DOMASK) {                                                            \
        const int kt_ = kb_ + (r & 3) + 8 * (r >> 2);                          \
        if (kt_ > qtok) v_ = -INFINITY;                                        \
      }                                                                        \
      p_[r] = __builtin_amdgcn_exp2f(v_);                                      \
    }                                                                          \
    _Pragma("unroll") for (int s = 0; s < 2; ++s) {                            \
      uint32_t a_ = pack_bf2(p_[8 * s + 0], p_[8 * s + 1]);                    \
      uint32_t b_ = pack_bf2(p_[8 * s + 2], p_[8 * s + 3]);                    \
      uint32_t c_ = pack_bf2(p_[8 * s + 4], p_[8 * s + 5]);                    \
      uint32_t d_ = pack_bf2(p_[8 * s + 6], p_[8 * s + 7]);                    \
      asm("v_permlane32_swap_b32 %0, %1" : "+v"(a_), "+v"(c_));                \
      asm("v_permlane32_swap_b32 %0, %1" : "+v"(b_), "+v"(d_));                \
      union { uint32_t u[4]; bf16x8 v8; } pu_;                                 \
      pu_.u[0] = a_; pu_.u[1] = b_; pu_.u[2] = c_; pu_.u[3] = d_;              \
      pa[2 * (KBLK) + s] = pu_.v8;                                             \
    }                                                                          \
  } while (0)

// one PV k-step (16 k-tokens): l += P.1 ; O += P V  (V B-frag rows = d)
#define PV_STEP(KS)                                                            \
  do {                                                                         \
    const int off_ = ((((KS) * 2 + lh) ^ sw) << 3);                            \
    const bf16x8 bv0_ =                                                        \
        *reinterpret_cast<const bf16x8*>(Vc + (size_t)l31 * 64 + off_);        \
    const bf16x8 bv1_ =                                                        \
        *reinterpret_cast<const bf16x8*>(Vc + (size_t)(32 + l31) * 64 + off_); \
    la = mfma32(pa[KS], vones, la);                                            \
    o0 = mfma32(pa[KS], bv0_, o0);                                             \
    o1 = mfma32(pa[KS], bv1_, o1);                                             \
  } while (0)

  STAGE(0, 0);

  int cur = 0;
  for (int tau = 0; tau < ntile; ++tau) {
    const int t0 = tau * 64;
    // implicit vmcnt(0)+lgkmcnt(0) drain: publishes buf[cur] DMA writes and
    // guarantees prior tile's LDS reads are done before next STAGE overwrite.
    __syncthreads();
    if (tau + 1 < ntile) STAGE(tau + 1, cur ^ 1);

    const unsigned short* Kc = Ks[cur];
    const unsigned short* Vc = Vts[cur];

    if (t0 <= qw + 31) {                 // wave has live q-rows in this tile
      const bool act1 = (t0 + 32 <= qw + 31);   // k-block 1 live?
      const bool m0 = (t0 + 31 > qw);           // k-block 0 needs masking?
      const bool m1 = (t0 + 63 > qw);           // k-block 1 needs masking?

      // ---- S^T = K Q^T: A = K rows (k-tokens), B = Q cols ----
      f32x16 st0 = {}, st1 = {};
      __builtin_amdgcn_s_setprio(1);
#pragma unroll
      for (int ks = 0; ks < 4; ++ks) {
        const bf16x8 ka = *reinterpret_cast<const bf16x8*>(
            Kc + (size_t)l31 * 64 + (((ks * 2 + lh) ^ sw) << 3));
        st0 = mfma32(ka, bq[ks], st0);
      }
      if (act1) {
#pragma unroll
        for (int ks = 0; ks < 4; ++ks) {
          const bf16x8 ka = *reinterpret_cast<const bf16x8*>(
              Kc + (size_t)(32 + l31) * 64 + (((ks * 2 + lh) ^ sw) << 3));
          st1 = mfma32(ka, bq[ks], st1);
        }
      }
      __builtin_amdgcn_s_setprio(0);

      // ---- exp + pack + swap -> pa[4] (in-register P, bf16 truncate) ----
      bf16x8 pa[4];
      EXP_PACK(st0, 0, m0);
      if (act1) EXP_PACK(st1, 1, m1);

      // ---- O += P V ; l += P . ones (MFMA pipe) ----
      __builtin_amdgcn_s_setprio(1);
      PV_STEP(0); PV_STEP(1);
      if (act1) { PV_STEP(2); PV_STEP(3); }
      __builtin_amdgcn_s_setprio(0);
    }
    cur ^= 1;
  }
#undef STAGE
#undef EXP_PACK
#undef PV_STEP

  // ---- epilogue: normalize in-register, store bf16 directly ----
  // o0/o1 C-layout: col = l31 (d), row reg r -> q = qw + (r&3)+8*(r>>2)+4*lh.
  // la[r] = row-sum (uniform across cols). Diagonal always present -> la > 0.
#pragma unroll
  for (int r = 0; r < 16; ++r) {
    const int q = qw + (r & 3) + 8 * (r >> 2) + 4 * lh;
    const float inv = 1.0f / la[r];
    unsigned short* orow = aob + ((size_t)b * NT + q) * NC + h * HS;
    orow[l31] = bft(o0[r] * inv);
    orow[32 + l31] = bft(o1[r] * inv);
  }
}

// ---------------- launch ----------------
extern "C" void kernel_launch(void* const* d_in, const int* in_sizes, int n_in,
                              void* d_out, int out_size, void* d_ws, size_t ws_size,
                              hipStream_t stream) {
  const float* x = (const float*)d_in[0];       // [B,T,C]
  const float* w_attn = (const float*)d_in[1];  // [C, 3C]
  const float* w_proj = (const float*)d_in[2];  // [C, C]
  float* outp = (float*)d_out;

  // ws layout (xb/waT die after gemm1; their space is simply unused after):
  char* w = (char*)d_ws;
  unsigned short* xb = (unsigned short*)w;                       // [MTOK][NC] bf16
  unsigned short* waT = xb + (size_t)MTOK * NC;                  // [NC][NC] bf16 (Q-scaled rows)
  float* lacc_unused = (float*)w;                                // kept for layout stability
  unsigned short* qkvb = (unsigned short*)((float*)w + (size_t)MTOK * NC + (size_t)NB * NHEAD * NT);
  unsigned short* aob  = qkvb + (size_t)MTOK * C3;               // [MTOK][NC] bf16
  unsigned short* vTb  = aob + (size_t)MTOK * NC;                // [B*NH][HS][T]
  unsigned short* wpT  = vTb + (size_t)MTOK * NC;                // [NC][NC] bf16
  (void)lacc_unused;

  // prep: 576 transpose tiles + x-cast blocks
  prep<<<576 + MTOK * NC / 4 / 256, 256, 0, stream>>>(x, w_attn, w_proj, xb, waT, wpT);

  // qkv = x @ w_attn (Q rows of waT pre-scaled); V blocks write vTb directly
  gemm128<1><<<dim3(C3 / 128, MTOK / 128), 256, 0, stream>>>(xb, waT, qkvb, vTb, MTOK, C3, NC);

  // attention: owner-block per q-tile, direct bf16 output (no atomics/finalize)
  attn<<<dim3(32, NHEAD, NB), 256, 0, stream>>>(qkvb, vTb, aob);

  // out = att_out @ w_proj -> fp32 d_out
  gemm128<0><<<dim3(NC / 128, MTOK / 128), 256, 0, stream>>>(aob, wpT, outp, nullptr, MTOK, NC, NC);
}

// Round 4
// 258.976 us; speedup vs baseline: 1.2116x; 1.1325x over previous
//
#include <hip/hip_runtime.h>
#include <hip/hip_bf16.h>
#include <stdint.h>

// Problem constants
#define NB 2
#define NT 4096
#define NC 768
#define NHEAD 12
#define HS 64
#define MTOK (NB * NT)      // 8192
#define C3 (3 * NC)         // 2304

typedef __bf16 bf16x8 __attribute__((ext_vector_type(8)));
typedef float f32x4 __attribute__((ext_vector_type(4)));
typedef float f32x16 __attribute__((ext_vector_type(16)));

#define KSCALE_LOG2E 0.18033688011f   // (1/sqrt(64)) * log2(e)

__device__ __forceinline__ unsigned short f2bf(float f) {  // RNE
  union { float f; uint32_t u; } v; v.f = f;
  uint32_t r = v.u + 0x7fffu + ((v.u >> 16) & 1u);
  return (unsigned short)(r >> 16);
}
__device__ __forceinline__ unsigned short bft(float f) {   // truncate
  return (unsigned short)(__builtin_bit_cast(unsigned int, f) >> 16);
}
// pack two floats as truncated bf16 pair: low short = a, high short = b
__device__ __forceinline__ uint32_t pack_bf2(float a, float b) {
  return (__builtin_bit_cast(uint32_t, b) & 0xffff0000u) |
         (__builtin_bit_cast(uint32_t, a) >> 16);
}

// async global->LDS, 16B per lane: lane i lands at ldsbase + i*16B.
__device__ __forceinline__ void gload_lds16(const unsigned short* g, unsigned short* ldsbase) {
  __builtin_amdgcn_global_load_lds(
      (const __attribute__((address_space(1))) unsigned int*)g,
      (__attribute__((address_space(3))) unsigned int*)ldsbase, 16, 0, 0);
}

__device__ __forceinline__ f32x4 mfma16(bf16x8 a, bf16x8 b, f32x4 c) {
  return __builtin_amdgcn_mfma_f32_16x16x32_bf16(a, b, c, 0, 0, 0);
}
__device__ __forceinline__ f32x16 mfma32(bf16x8 a, bf16x8 b, f32x16 c) {
  return __builtin_amdgcn_mfma_f32_32x32x16_bf16(a, b, c, 0, 0, 0);
}

// ---------------- prep: coalesced LDS-tiled transposes + x cast ----------------
__global__ __launch_bounds__(256) void prep(
    const float* __restrict__ x, const float* __restrict__ wa, const float* __restrict__ wp,
    unsigned short* __restrict__ xb, unsigned short* __restrict__ waT,
    unsigned short* __restrict__ wpT) {
  const int bx = blockIdx.x;
  if (bx < 576) {
    __shared__ float tile[64][65];
    const float* src; unsigned short* dst;
    int srcN, dstN, k0, n0, qscale;
    if (bx < 432) {
      src = wa; dst = waT; srcN = C3; dstN = NC; qscale = 1;
      k0 = (bx / 36) * 64; n0 = (bx % 36) * 64;
    } else {
      const int t = bx - 432;
      src = wp; dst = wpT; srcN = NC; dstN = NC; qscale = 0;
      k0 = (t / 12) * 64; n0 = (t % 12) * 64;
    }
    const int tr = threadIdx.x >> 4;        // 0..15
    const int tc = (threadIdx.x & 15) * 4;  // 0,4,..,60
#pragma unroll
    for (int p = 0; p < 4; ++p) {
      const int r = p * 16 + tr;
      const float4 v = *reinterpret_cast<const float4*>(src + (size_t)(k0 + r) * srcN + n0 + tc);
      tile[r][tc + 0] = v.x; tile[r][tc + 1] = v.y;
      tile[r][tc + 2] = v.z; tile[r][tc + 3] = v.w;
    }
    __syncthreads();
#pragma unroll
    for (int p = 0; p < 4; ++p) {
      const int n = p * 16 + tr;   // output row = source column n0+n
      const float sc = (qscale && (n0 + n) < NC) ? KSCALE_LOG2E : 1.0f;
      ushort4 o;
      o.x = f2bf(tile[tc + 0][n] * sc); o.y = f2bf(tile[tc + 1][n] * sc);
      o.z = f2bf(tile[tc + 2][n] * sc); o.w = f2bf(tile[tc + 3][n] * sc);
      *reinterpret_cast<ushort4*>(dst + (size_t)(n0 + n) * dstN + k0 + tc) = o;
    }
  } else {
    const int gid = (bx - 576) * 256 + threadIdx.x;   // < MTOK*NC/4
    const float4 v = reinterpret_cast<const float4*>(x)[gid];
    ushort4 o;
    o.x = f2bf(v.x); o.y = f2bf(v.y); o.z = f2bf(v.z); o.w = f2bf(v.w);
    reinterpret_cast<ushort4*>(xb)[gid] = o;
  }
}

// ---------------- GEMM 128x128: C[M,N] = A[M,K] @ Bt[N,K]^T ----------------
// OUT_BF16=1 (gemm1): blocks with col0 >= 2*NC hold the V tile -> transpose
// in-block via smem (16B-chunk XOR swizzle) and write straight to vT
// [B*NH][HS][T]; qkvb's V slice is never written. Other blocks write qkvb rows.
template <int OUT_BF16>
__global__ __launch_bounds__(256) void gemm128(
    const unsigned short* __restrict__ A,   // [M][K]
    const unsigned short* __restrict__ Bt,  // [N][K]
    void* __restrict__ Cout,
    unsigned short* __restrict__ vT,        // used only by OUT_BF16 V-blocks
    int M, int N, int K) {
  __shared__ unsigned short smem[2 * 128 * 64];
  unsigned short* As = smem;
  unsigned short* Bs = smem + 128 * 64;

  const int tid = threadIdx.x;
  const int wave = tid >> 6;
  const int lane = tid & 63;
  const int li = lane & 15;
  const int lq = lane >> 4;
  const int wm = wave & 1;
  const int wn = wave >> 1;
  const int row0 = blockIdx.y * 128;
  const int col0 = blockIdx.x * 128;

  const int crow = lane >> 3;
  const int cchunk = ((lane & 7) ^ crow) * 8;

  f32x4 acc[4][4] = {};

  for (int k0 = 0; k0 < K; k0 += 64) {
#pragma unroll
    for (int i = 0; i < 4; ++i) {
      const int R = wave * 32 + i * 8;
      gload_lds16(A + (size_t)(row0 + R + crow) * K + k0 + cchunk, &As[R * 64]);
      gload_lds16(Bt + (size_t)(col0 + R + crow) * K + k0 + cchunk, &Bs[R * 64]);
    }
    __syncthreads();

#pragma unroll
    for (int ks = 0; ks < 2; ++ks) {
      bf16x8 af[4], bf[4];
#pragma unroll
      for (int f = 0; f < 4; ++f) {
        const int arow = wm * 64 + f * 16 + li;
        af[f] = *reinterpret_cast<const bf16x8*>(&As[arow * 64 + (((ks * 4 + lq) ^ (li & 7)) << 3)]);
        const int brow = wn * 64 + f * 16 + li;
        bf[f] = *reinterpret_cast<const bf16x8*>(&Bs[brow * 64 + (((ks * 4 + lq) ^ (li & 7)) << 3)]);
      }
#pragma unroll
      for (int fa = 0; fa < 4; ++fa)
#pragma unroll
        for (int fb = 0; fb < 4; ++fb)
          acc[fa][fb] = mfma16(af[fa], bf[fb], acc[fa][fb]);
    }
    __syncthreads();   // also protects smem reuse in the fused epilogue
  }

  if (OUT_BF16) {
    if (col0 >= 2 * NC) {
      // ---- fused V transpose: acc -> smem[c][t] -> vT[bh][d][t] ----
      const int b = row0 >> 12;            // row0 / NT
      const int t0r = row0 & (NT - 1);
      const int h0 = (col0 - 2 * NC) >> 6;
      // write phase: value at (c = head-col, t = token) with 16B-chunk XOR swizzle
#pragma unroll
      for (int fa = 0; fa < 4; ++fa) {
#pragma unroll
        for (int fb = 0; fb < 4; ++fb) {
          const int cc = wn * 64 + fb * 16 + li;
#pragma unroll
          for (int r = 0; r < 4; ++r) {
            const int tt = wm * 64 + fa * 16 + lq * 4 + r;
            const int slot = cc * 16 + ((tt >> 3) ^ (cc & 15));
            smem[slot * 8 + (tt & 7)] = f2bf(acc[fa][fb][r]);
          }
        }
      }
      __syncthreads();
      // read phase: 16 lanes cover one c-row's 16 chunks -> 256B coalesced stores
      const int ch = tid & 15;
#pragma unroll
      for (int j = 0; j < 8; ++j) {
        const int cc = (tid >> 4) + 16 * j;
        const uint4 v = *reinterpret_cast<const uint4*>(
            smem + (size_t)(cc * 16 + (ch ^ (cc & 15))) * 8);
        const int bh = b * NHEAD + h0 + (cc >> 6);
        const int d = cc & 63;
        *reinterpret_cast<uint4*>(vT + (size_t)bh * HS * NT + (size_t)d * NT + t0r + ch * 8) = v;
      }
    } else {
      unsigned short* Cb = (unsigned short*)Cout;
#pragma unroll
      for (int fa = 0; fa < 4; ++fa) {
        const int gr = row0 + wm * 64 + fa * 16 + lq * 4;
#pragma unroll
        for (int fb = 0; fb < 4; ++fb) {
          const int gc = col0 + wn * 64 + fb * 16 + li;
#pragma unroll
          for (int r = 0; r < 4; ++r)
            Cb[(size_t)(gr + r) * N + gc] = f2bf(acc[fa][fb][r]);
        }
      }
    }
  } else {
    float* Cf = (float*)Cout;
#pragma unroll
    for (int fa = 0; fa < 4; ++fa) {
      const int gr = row0 + wm * 64 + fa * 16 + lq * 4;
#pragma unroll
      for (int fb = 0; fb < 4; ++fb) {
        const int gc = col0 + wn * 64 + fb * 16 + li;
#pragma unroll
        for (int r = 0; r < 4; ++r)
          Cf[(size_t)(gr + r) * N + gc] = acc[fa][fb][r];
      }
    }
  }
}

// ---------------- Flash attention: balanced items + 3-deep counted-vmcnt pipeline ----
// Work items (48 per (b,h), 1152 blocks):
//   idx  0..31: qi = 31 - idx/2 (>=16), KV range split in half (17..33 tiles)
//               -> partial accumulate into Oacc/lacc via fp32 atomics.
//   idx 32..47: qi = 47 - idx (<16), whole triangle (2..32 tiles)
//               -> normalize in-register, store bf16 directly to aob.
// XCD-chunked bijective remap: w = (bid&7)*144 + bid/8 puts each (b,h)'s 48
// items on one XCD (K/V L2 reuse), largest-first within XCD.
// Inner loop: 3-deep LDS buffers; per tile: s_waitcnt vmcnt(4) (tile tau
// landed, tau+1 still in flight) -> raw s_barrier -> issue STAGE(tau+2) ->
// compute. vmcnt(0) only on the last tile. Loads get ~2 tiles to land.

__global__ __launch_bounds__(256) void attn(
    const unsigned short* __restrict__ qkv,   // [B][T][3C] (V slice unused)
    const unsigned short* __restrict__ vT,    // [B*NH][HS][T]
    float* __restrict__ Oacc,                 // [MTOK][NC] fp32, zeroed (split rows)
    float* __restrict__ lacc,                 // [B*NH][NT]  fp32, zeroed
    unsigned short* __restrict__ aob) {       // [MTOK][NC] bf16 out (direct rows)
  __shared__ unsigned short Ks[3][64 * 64];
  __shared__ unsigned short Vts[3][64 * 64];

  const int tid = threadIdx.x;
  const int wave = tid >> 6;
  const int lane = tid & 63;
  const int l31 = lane & 31;
  const int lh = lane >> 5;
  const int sw = l31 & 7;                     // XOR-swizzle key for frag reads

  // ---- work decode (XCD-chunked, bijective: 1152 = 8 * 144) ----
  const int bid = (int)blockIdx.x;
  const int w = (bid & 7) * 144 + (bid >> 3);
  const int grp = w / 48;                     // 0..23 = b*12+h
  const int idx = w - grp * 48;
  const int b = grp / 12;
  const int h = grp - b * 12;
  int qi, tauS, tauE, split;
  if (idx < 32) {
    split = 1;
    qi = 31 - (idx >> 1);                     // 31..16
    const int nt = 2 * qi + 2;
    if (idx & 1) { tauS = nt >> 1; tauE = nt; }
    else         { tauS = 0;       tauE = nt >> 1; }
  } else {
    split = 0;
    qi = 47 - idx;                            // 15..0
    tauS = 0; tauE = 2 * qi + 2;
  }
  const int q0 = qi * 128;
  const int bh = b * NHEAD + h;

  const size_t baseQ = (size_t)b * NT * C3 + (size_t)h * HS;
  const size_t baseK = baseQ + NC;
  const unsigned short* kq = qkv + baseK;
  const unsigned short* vbase = vT + (size_t)bh * HS * NT;

  const int qw = q0 + wave * 32;              // wave's first q row
  const int qtok = qw + l31;                  // this lane's q token

  // Q B-fragments (pre-scaled via waT): lane holds Q[q=qw+l31][ks*16+lh*8..+7]
  bf16x8 bq[4];
#pragma unroll
  for (int ks = 0; ks < 4; ++ks)
    bq[ks] = *reinterpret_cast<const bf16x8*>(
        qkv + baseQ + (size_t)(qw + l31) * C3 + ks * 16 + lh * 8);

  // all-ones B fragment for l row-sums on the MFMA pipe
  bf16x8 vones;
#pragma unroll
  for (int i = 0; i < 8; ++i) vones[i] = (__bf16)1.0f;

  f32x16 o0 = {}, o1 = {}, la = {};

  // ---- gload staging geometry: per wave, 2 calls x 8 rows for K and V ----
  // DMA writes linear (wave-uniform LDS base + lane*16B); the XOR swizzle is
  // applied on the per-lane GLOBAL address instead: LDS[R][c] = G[R][c^(R&7)].
  const int grow = lane >> 3;               // row within 8-row group
  const int gch = (lane & 7) ^ grow;        // pre-swizzled 16B chunk
  const int wr0 = wave * 8;                 // uniform row bases
  const int wr1 = wave * 8 + 32;

#define STAGE(TAU, BUFI)                                                        \
  do {                                                                          \
    const int t0s_ = (TAU) * 64;                                                \
    gload_lds16(kq + (size_t)(t0s_ + wr0 + grow) * C3 + gch * 8,                \
                &Ks[BUFI][wr0 * 64]);                                           \
    gload_lds16(kq + (size_t)(t0s_ + wr1 + grow) * C3 + gch * 8,                \
                &Ks[BUFI][wr1 * 64]);                                           \
    gload_lds16(vbase + (size_t)(wr0 + grow) * NT + t0s_ + gch * 8,             \
                &Vts[BUFI][wr0 * 64]);                                          \
    gload_lds16(vbase + (size_t)(wr1 + grow) * NT + t0s_ + gch * 8,             \
                &Vts[BUFI][wr1 * 64]);                                          \
  } while (0)

// exp + pack + permlane-swap one 32-k block (16 S^T regs) into pa[2*KBLK+s].
#define EXP_PACK(ST, KBLK, DOMASK)                                             \
  do {                                                                         \
    const int kb_ = t0 + (KBLK) * 32 + 4 * lh;                                 \
    float p_[16];                                                              \
    _Pragma("unroll") for (int r = 0; r < 16; ++r) {                           \
      float v_ = (ST)[r];                                                      \
      if (DOMASK) {                                                            \
        const int kt_ = kb_ + (r & 3) + 8 * (r >> 2);                          \
        if (kt_ > qtok) v_ = -INFINITY;                                        \
      }                                                                        \
      p_[r] = __builtin_amdgcn_exp2f(v_);                                      \
    }                                                                          \
    _Pragma("unroll") for (int s = 0; s < 2; ++s) {                            \
      uint32_t a_ = pack_bf2(p_[8 * s + 0], p_[8 * s + 1]);                    \
      uint32_t b_ = pack_bf2(p_[8 * s + 2], p_[8 * s + 3]);                    \
      uint32_t c_ = pack_bf2(p_[8 * s + 4], p_[8 * s + 5]);                    \
      uint32_t d_ = pack_bf2(p_[8 * s + 6], p_[8 * s + 7]);                    \
      asm("v_permlane32_swap_b32 %0, %1" : "+v"(a_), "+v"(c_));                \
      asm("v_permlane32_swap_b32 %0, %1" : "+v"(b_), "+v"(d_));                \
      union { uint32_t u[4]; bf16x8 v8; } pu_;                                 \
      pu_.u[0] = a_; pu_.u[1] = b_; pu_.u[2] = c_; pu_.u[3] = d_;              \
      pa[2 * (KBLK) + s] = pu_.v8;                                             \
    }                                                                          \
  } while (0)

// one PV k-step (16 k-tokens): l += P.1 ; O += P V  (V B-frag rows = d)
#define PV_STEP(KS)                                                            \
  do {                                                                         \
    const int off_ = ((((KS) * 2 + lh) ^ sw) << 3);                            \
    const bf16x8 bv0_ =                                                        \
        *reinterpret_cast<const bf16x8*>(Vc + (size_t)l31 * 64 + off_);        \
    const bf16x8 bv1_ =                                                        \
        *reinterpret_cast<const bf16x8*>(Vc + (size_t)(32 + l31) * 64 + off_); \
    la = mfma32(pa[KS], vones, la);                                            \
    o0 = mfma32(pa[KS], bv0_, o0);                                             \
    o1 = mfma32(pa[KS], bv1_, o1);                                             \
  } while (0)

  // prologue: 2 tiles in flight (tauE - tauS >= 2 always)
  STAGE(tauS, 0);
  STAGE(tauS + 1, 1);

  int cur = 0;
  for (int tau = tauS; tau < tauE; ++tau) {
    const int t0 = tau * 64;
    // counted drain: tile tau's 4 loads landed; tau+1's stay in flight.
    if (tau + 1 < tauE) asm volatile("s_waitcnt vmcnt(4)" ::: "memory");
    else                asm volatile("s_waitcnt vmcnt(0)" ::: "memory");
    __builtin_amdgcn_s_barrier();          // publish buf[cur] to all waves
    __builtin_amdgcn_sched_barrier(0);     // no hoisting across the barrier
    if (tau + 2 < tauE) {
      int nb = cur + 2; if (nb >= 3) nb -= 3;   // overwrites buf read at tau-1
      STAGE(tau + 2, nb);
    }

    const unsigned short* Kc = Ks[cur];
    const unsigned short* Vc = Vts[cur];

    if (t0 <= qw + 31) {                 // wave has live q-rows in this tile
      const bool act1 = (t0 + 32 <= qw + 31);   // k-block 1 live?
      const bool m0 = (t0 + 31 > qw);           // k-block 0 needs masking?
      const bool m1 = (t0 + 63 > qw);           // k-block 1 needs masking?

      // ---- S^T = K Q^T: A = K rows (k-tokens), B = Q cols ----
      f32x16 st0 = {}, st1 = {};
      __builtin_amdgcn_s_setprio(1);
#pragma unroll
      for (int ks = 0; ks < 4; ++ks) {
        const bf16x8 ka = *reinterpret_cast<const bf16x8*>(
            Kc + (size_t)l31 * 64 + (((ks * 2 + lh) ^ sw) << 3));
        st0 = mfma32(ka, bq[ks], st0);
      }
      if (act1) {
#pragma unroll
        for (int ks = 0; ks < 4; ++ks) {
          const bf16x8 ka = *reinterpret_cast<const bf16x8*>(
              Kc + (size_t)(32 + l31) * 64 + (((ks * 2 + lh) ^ sw) << 3));
          st1 = mfma32(ka, bq[ks], st1);
        }
      }
      __builtin_amdgcn_s_setprio(0);

      // ---- exp + pack + swap -> pa[4] (in-register P, bf16 truncate) ----
      bf16x8 pa[4];
      EXP_PACK(st0, 0, m0);
      if (act1) EXP_PACK(st1, 1, m1);

      // ---- O += P V ; l += P . ones (MFMA pipe) ----
      __builtin_amdgcn_s_setprio(1);
      PV_STEP(0); PV_STEP(1);
      if (act1) { PV_STEP(2); PV_STEP(3); }
      __builtin_amdgcn_s_setprio(0);
    }
    ++cur; if (cur == 3) cur = 0;
  }
#undef STAGE
#undef EXP_PACK
#undef PV_STEP

  // ---- epilogue ----
  // o0/o1 C-layout: col = l31 (d), reg r -> q = qw + (r&3)+8*(r>>2)+4*lh.
  // la[r] = row-sum, uniform across l31.
  if (split) {
    const size_t obase = (size_t)b * NT * NC + (size_t)h * HS;
    float* lrow = lacc + (size_t)bh * NT;
#pragma unroll
    for (int r = 0; r < 16; ++r) {
      const int q = qw + (r & 3) + 8 * (r >> 2) + 4 * lh;
      if (l31 == 0) atomicAdd(&lrow[q], la[r]);
      atomicAdd(&Oacc[obase + (size_t)q * NC + l31], o0[r]);
      atomicAdd(&Oacc[obase + (size_t)q * NC + 32 + l31], o1[r]);
    }
  } else {
#pragma unroll
    for (int r = 0; r < 16; ++r) {
      const int q = qw + (r & 3) + 8 * (r >> 2) + 4 * lh;
      const float inv = 1.0f / la[r];
      unsigned short* orow = aob + ((size_t)b * NT + q) * NC + h * HS;
      orow[l31] = bft(o0[r] * inv);
      orow[32 + l31] = bft(o1[r] * inv);
    }
  }
}

// ---------------- finalize: aob = bf16(Oacc / l) for split rows (q >= NT/2) ----
__global__ __launch_bounds__(256) void finalize(
    const float* __restrict__ Oacc, const float* __restrict__ lacc,
    unsigned short* __restrict__ aob) {
  const int idx4 = (blockIdx.x * 256 + threadIdx.x);
  if (idx4 >= NB * (NT / 2) * NC / 4) return;
  const int idx = idx4 * 4;
  const int rowp = idx / NC;          // 0 .. NB*NT/2-1
  const int cc = idx - rowp * NC;
  const int b = rowp >> 11;           // NT/2 = 2048
  const int t = (NT / 2) + (rowp & 2047);
  const int h = cc >> 6;
  const float inv = 1.0f / lacc[(size_t)(b * NHEAD + h) * NT + t];
  const size_t base = ((size_t)b * NT + t) * NC + cc;
  const float4 v = *reinterpret_cast<const float4*>(Oacc + base);
  ushort4 o;
  o.x = bft(v.x * inv); o.y = bft(v.y * inv);
  o.z = bft(v.z * inv); o.w = bft(v.w * inv);
  *reinterpret_cast<ushort4*>(aob + base) = o;
}

// ---------------- launch ----------------
extern "C" void kernel_launch(void* const* d_in, const int* in_sizes, int n_in,
                              void* d_out, int out_size, void* d_ws, size_t ws_size,
                              hipStream_t stream) {
  const float* x = (const float*)d_in[0];       // [B,T,C]
  const float* w_attn = (const float*)d_in[1];  // [C, 3C]
  const float* w_proj = (const float*)d_in[2];  // [C, C]
  float* outp = (float*)d_out;

  // ws layout (Oacc aliases xb/waT, which die after gemm1):
  char* w = (char*)d_ws;
  float* Oacc = (float*)w;
  unsigned short* xb = (unsigned short*)w;                       // aliases Oacc (pre-attn)
  unsigned short* waT = xb + (size_t)MTOK * NC;                  // aliases Oacc tail
  float* lacc = Oacc + (size_t)MTOK * NC;
  unsigned short* qkvb = (unsigned short*)(lacc + (size_t)NB * NHEAD * NT);
  unsigned short* aob  = qkvb + (size_t)MTOK * C3;               // [MTOK][NC] bf16
  unsigned short* vTb  = aob + (size_t)MTOK * NC;                // [B*NH][HS][T]
  unsigned short* wpT  = vTb + (size_t)MTOK * NC;                // [NC][NC] bf16

  // prep: 576 transpose tiles + x-cast blocks
  prep<<<576 + MTOK * NC / 4 / 256, 256, 0, stream>>>(x, w_attn, w_proj, xb, waT, wpT);

  // qkv = x @ w_attn (Q rows of waT pre-scaled); V blocks write vTb directly
  gemm128<1><<<dim3(C3 / 128, MTOK / 128), 256, 0, stream>>>(xb, waT, qkvb, vTb, MTOK, C3, NC);

  // zero partial accumulators (xb/waT now dead; only split rows are read)
  hipMemsetAsync(Oacc, 0, ((size_t)MTOK * NC + (size_t)NB * NHEAD * NT) * sizeof(float), stream);

  // attention: 1152 balanced items (split-KV for qi>=16, owner-block for qi<16)
  attn<<<1152, 256, 0, stream>>>(qkvb, vTb, Oacc, lacc, aob);

  // normalize split rows -> bf16 aob
  finalize<<<(NB * (NT / 2) * NC / 4 + 255) / 256, 256, 0, stream>>>(Oacc, lacc, aob);

  // out = att_out @ w_proj -> fp32 d_out
  gemm128<0><<<dim3(NC / 128, MTOK / 128), 256, 0, stream>>>(aob, wpT, outp, nullptr, MTOK, NC, NC);
}